// Round 6
// baseline (381.735 us; speedup 1.0000x reference)
//
#include <hip/hip_runtime.h>
#include <hip/hip_bf16.h>

#define EMB   1024
#define NHEAD 16
#define HDIM  64
#define BSZ   4
#define SEQ   2048
#define MROWS (BSZ*SEQ)     // 8192
#define NQKV  (3*EMB)       // 3072

typedef __bf16 bf16;
typedef __bf16 bf16v4 __attribute__((ext_vector_type(4)));
typedef __bf16 bf16v8 __attribute__((ext_vector_type(8)));
typedef float  f32v4  __attribute__((ext_vector_type(4)));
typedef int    i32v4  __attribute__((ext_vector_type(4)));

#define MFMA16(a,b,c)  __builtin_amdgcn_mfma_f32_16x16x32_bf16((a),(b),(c),0,0,0)
#define MFMAI8(a,b,c)  __builtin_amdgcn_mfma_i32_16x16x64_i8((a),(b),(c),0,0,0)

__device__ __forceinline__ void gload_lds16(const void* g, void* l) {
  __builtin_amdgcn_global_load_lds((const __attribute__((address_space(1))) void*)g,
                                   (__attribute__((address_space(3))) void*)l,
                                   16, 0, 0);
}

// ---------------- scale reduction + ternarize + quantize ----------------

__global__ void zero2_kernel(float* p) { p[threadIdx.x] = 0.f; }

__global__ void abs_sum_kernel(const float* __restrict__ w, int n, float* out) {
  float s = 0.f;
  for (int i = blockIdx.x * blockDim.x + threadIdx.x; i < n; i += gridDim.x * blockDim.x)
    s += fabsf(w[i]);
  #pragma unroll
  for (int off = 32; off; off >>= 1) s += __shfl_down(s, off, 64);
  __shared__ float red[4];
  int lane = threadIdx.x & 63, wid = threadIdx.x >> 6;
  if (lane == 0) red[wid] = s;
  __syncthreads();
  if (threadIdx.x == 0) atomicAdd(out, red[0] + red[1] + red[2] + red[3]);
}

// ternary weights as i8 (exact)
__global__ void ternarize_i8_kernel(const float* __restrict__ w, int n,
                                    const float* __restrict__ sum, char* __restrict__ out) {
  int i = blockIdx.x * blockDim.x + threadIdx.x;
  if (i >= n) return;
  float scale = fmaxf(*sum / (float)n, 1e-8f);
  float t = rintf(w[i] / scale);          // RNE == jnp.round
  t = fmaxf(-1.f, fminf(1.f, t));
  out[i] = (char)(int)t;
}

// ternary weights as bf16 (for the bf16 out-projection GEMM)
__global__ void ternarize_bf16_kernel(const float* __restrict__ w, int n,
                                      const float* __restrict__ sum, bf16* __restrict__ out) {
  int i = blockIdx.x * blockDim.x + threadIdx.x;
  if (i >= n) return;
  float scale = fmaxf(*sum / (float)n, 1e-8f);
  float t = rintf(w[i] / scale);
  t = fmaxf(-1.f, fminf(1.f, t));
  out[i] = (bf16)t;
}

// x -> two i8 planes: x ~= p1/16 + p2/4096 (|err| <= 2.4e-4; exact i32 MFMA accum)
__global__ void quant_x_kernel(const float* __restrict__ x, char* __restrict__ p1,
                               char* __restrict__ p2, int n) {
  int i = blockIdx.x * blockDim.x + threadIdx.x;
  if (i >= n) return;
  float v = x[i];
  float q1 = fminf(fmaxf(rintf(v * 16.f), -127.f), 127.f);
  float r = v - q1 * 0.0625f;
  float q2 = fminf(fmaxf(rintf(r * 4096.f), -127.f), 127.f);
  p1[i] = (char)(int)q1;
  p2[i] = (char)(int)q2;
}

// ---------------- fused QKV GEMM, dual-plane i8 (unchanged) ----------------

__launch_bounds__(256, 2)
__global__ void gemm_qkv_kernel(const char* __restrict__ xq1, const char* __restrict__ xq2,
                                const char* __restrict__ w8,
                                bf16* __restrict__ qh, bf16* __restrict__ ql,
                                bf16* __restrict__ kh, bf16* __restrict__ kl,
                                bf16* __restrict__ vv) {
  __shared__ __align__(16) char A1[128 * 64];
  __shared__ __align__(16) char A2[128 * 64];
  __shared__ __align__(16) char Bs[128 * 64];
  const int tid = threadIdx.x;
  const int lane = tid & 63, wid = tid >> 6;
  const int quad = lane >> 4, l16 = lane & 15;
  const int m0 = blockIdx.x * 128, n0 = blockIdx.y * 128;
  const int wm = (wid >> 1) * 64, wn = (wid & 1) * 64;
  const int asw = (l16 >> 1) & 3;         // fragment-read swizzle
  i32v4 acc1[4][4] = {};
  i32v4 acc2[4][4] = {};

  for (int kt = 0; kt < EMB / 64; ++kt) {
    __syncthreads();
    #pragma unroll
    for (int r = 0; r < 2; ++r) {
      int li = r * 256 + tid;
      int row = li >> 2, cs = li & 3;
      int cg = cs ^ ((row >> 1) & 3);
      gload_lds16(xq1 + (size_t)(m0 + row) * EMB + kt * 64 + cg * 16, &A1[li * 16]);
      gload_lds16(xq2 + (size_t)(m0 + row) * EMB + kt * 64 + cg * 16, &A2[li * 16]);
      gload_lds16(w8  + (size_t)(n0 + row) * EMB + kt * 64 + cg * 16, &Bs[li * 16]);
    }
    __syncthreads();
    i32v4 af1[4], af2[4], bfr[4];
    #pragma unroll
    for (int i = 0; i < 4; ++i) {
      int arow = wm + i * 16 + l16;
      int off = arow * 64 + ((quad ^ asw) * 16);
      af1[i] = *(const i32v4*)&A1[off];
      af2[i] = *(const i32v4*)&A2[off];
      int brow = wn + i * 16 + l16;
      bfr[i] = *(const i32v4*)&Bs[brow * 64 + ((quad ^ asw) * 16)];
    }
    #pragma unroll
    for (int i = 0; i < 4; ++i)
      #pragma unroll
      for (int j = 0; j < 4; ++j) {
        acc1[i][j] = MFMAI8(af1[i], bfr[j], acc1[i][j]);
        acc2[i][j] = MFMAI8(af2[i], bfr[j], acc2[i][j]);
      }
  }
  const float S1 = 0.0625f, S2 = 1.f / 4096.f;
  const float QSCALE = 0.18033688011112042f;   // 0.125 * log2(e)
  #pragma unroll
  for (int i = 0; i < 4; ++i)
    #pragma unroll
    for (int j = 0; j < 4; ++j)
      #pragma unroll
      for (int r = 0; r < 4; ++r) {
        int m = m0 + wm + i * 16 + quad * 4 + r;
        int n = n0 + wn + j * 16 + l16;
        float c = (float)acc1[i][j][r] * S1 + (float)acc2[i][j][r] * S2;
        int b = m >> 11, t = m & (SEQ - 1);
        int region = n >> 10, c1 = n & 1023, h = c1 >> 6, d = c1 & 63;
        size_t idx = (((size_t)(b * NHEAD + h) * SEQ + t) << 6) + d;
        if (region == 0)      { float cs = c * QSCALE; bf16 hi = (bf16)cs; qh[idx] = hi; ql[idx] = (bf16)(cs - (float)hi); }
        else if (region == 1) { bf16 hi = (bf16)c; kh[idx] = hi; kl[idx] = (bf16)(c - (float)hi); }
        else                  { vv[idx] = (bf16)c; }
      }
}

// ---------------- V transpose: [B,H,T,D] -> [B,H,D,T] ----------------

__global__ void transpose_v_kernel(const bf16* __restrict__ v, bf16* __restrict__ vt) {
  __shared__ bf16 tile[64 * 72];
  const int tid = threadIdx.x;
  const int bh = blockIdx.y, t0 = blockIdx.x * 64;
  const size_t base = (size_t)bh * SEQ * HDIM;
  #pragma unroll
  for (int r = 0; r < 2; ++r) {
    int li = r * 256 + tid;
    int row = li >> 3, col = (li & 7) * 8;
    bf16v8 val = *(const bf16v8*)(v + base + (size_t)(t0 + row) * HDIM + col);
    #pragma unroll
    for (int j = 0; j < 8; ++j) tile[(col + j) * 72 + row] = val[j];
  }
  __syncthreads();
  #pragma unroll
  for (int r = 0; r < 2; ++r) {
    int li = r * 256 + tid;
    int drow = li >> 3, tcol = (li & 7) * 8;
    bf16v8 val;
    #pragma unroll
    for (int j = 0; j < 8; ++j) val[j] = tile[drow * 72 + tcol + j];
    *(bf16v8*)(vt + base + (size_t)drow * SEQ + t0 + tcol) = val;
  }
}

// ---------------- Flash attention ----------------
// Register-P flash attention, zero-shuffle PV:
//  - swapped QK^T (mfma(K,Q)): lane-local q-rows, in-lane softmax (R4-verified)
//  - P stays in registers IN-PLACE: with PV k-slot permutation
//      slot(kk,quad,j) <-> key kk*32 + (j>>2)*16 + quad*4 + (j&3)
//    the QK^T C-layout output IS the PV A-fragment (no shuffles, no LDS).
//  - V side matches the permutation: two ds_read_b64 chunks per (kk,dt)
//    (cols kk*32+quad*4 and +16) instead of one b128.
//  - P buffer dropped -> LDS 49152 -> 3 blocks/CU (2->3 waves/SIMD)

__launch_bounds__(256, 3)
__global__ void attn_kernel(const bf16* __restrict__ qh, const bf16* __restrict__ ql,
                            const bf16* __restrict__ kh, const bf16* __restrict__ kl,
                            const bf16* __restrict__ vt, bf16* __restrict__ o) {
  __shared__ __align__(16) char smem[49152];
  // buf b at smem + b*24576: Kh [0,8K) | Kl [8K,16K) | Vt [16K,24K)
  bf16* Qh = (bf16*)smem;               // Q phase overlay (dead after frag read)
  bf16* Ql = (bf16*)(smem + 16384);
  const int tid = threadIdx.x;
  const int lane = tid & 63, wid = tid >> 6;     // 4 waves
  const int quad = lane >> 4, l16 = lane & 15;
  const int xs = l16 & 7;
  const int pair = blockIdx.x;          // 0..7
  const int bh = blockIdx.y;
  const size_t base = (size_t)bh * SEQ * HDIM;

  auto stage_kv = [&](char* dst, int k0) {
    #pragma unroll
    for (int r = 0; r < 2; ++r) {
      int li = r * 256 + tid;
      int srow = li >> 3, scg = (li & 7) ^ (srow & 7);
      gload_lds16(kh + base + (size_t)(k0 + srow) * HDIM + scg * 8, (bf16*)dst + (size_t)li * 8);
      gload_lds16(kl + base + (size_t)(k0 + srow) * HDIM + scg * 8, (bf16*)(dst + 8192) + (size_t)li * 8);
      gload_lds16(vt + base + (size_t)srow * SEQ + k0 + scg * 8,    (bf16*)(dst + 16384) + (size_t)li * 8);
    }
  };

  const int b = bh >> 4, h = bh & 15;
  union pb8 { bf16v8 v; int w[4]; };

  for (int phase = 0; phase < 2; ++phase) {
    const int qt = phase ? (7 - pair) : (8 + pair);
    const int q0 = qt * 128;

    __syncthreads();                    // prior phase's LDS readers done
    // stage Q (hi+lo), swizzled
    #pragma unroll
    for (int r = 0; r < 4; ++r) {
      int li = r * 256 + tid;
      int row = li >> 3, cg = (li & 7) ^ (row & 7);
      gload_lds16(qh + base + (size_t)(q0 + row) * HDIM + cg * 8, &Qh[li * 8]);
      gload_lds16(ql + base + (size_t)(q0 + row) * HDIM + cg * 8, &Ql[li * 8]);
    }
    __syncthreads();
    bf16v8 qhf[2][2], qlf[2][2];
    #pragma unroll
    for (int sub = 0; sub < 2; ++sub)
      #pragma unroll
      for (int kk = 0; kk < 2; ++kk) {
        int off = (wid * 32 + sub * 16 + l16) * 64 + (((kk << 2) | quad) ^ xs) * 8;
        qhf[sub][kk] = *(const bf16v8*)&Qh[off];
        qlf[sub][kk] = *(const bf16v8*)&Ql[off];
      }
    __syncthreads();                    // all waves hold Q frags; bufs free

    f32v4 oacc[2][4] = {};
    float lsum[2] = {0.f, 0.f};
    float mrow[2] = {-1e30f, -1e30f};

    const int qw0 = q0 + wid * 32;
    const int qrow_hi = qw0 + 31;       // wave-uniform causal limit (covers both subs)
    const int ntiles = 2 * qt + 2;

    stage_kv(smem, 0);                  // preload tile 0 -> buf0 (cold drain once)

    for (int ktile = 0; ktile < ntiles; ++ktile) {
      char* cb = smem + (size_t)((ktile & 1) * 24576);
      char* nb = smem + (size_t)(((ktile + 1) & 1) * 24576);
      __syncthreads();                  // tile ktile staged (all waves); prev buf free
      if (ktile + 1 < ntiles) stage_kv(nb, (ktile + 1) * 64);   // prefetch, in flight
      const int k0 = ktile * 64;
      if (k0 > qrow_hi) continue;       // fully-masked tile for this wave

      bf16* Kh_ = (bf16*)cb;
      bf16* Kl_ = (bf16*)(cb + 8192);
      bf16* Vt_ = (bf16*)(cb + 16384);

      // ---- QK^T swapped: C[row=key][col=q-row]; K frags read once ----
      f32v4 sacc[2][4] = {};
      #pragma unroll
      for (int kk = 0; kk < 2; ++kk) {
        const int co = (((kk << 2) | quad) ^ xs) * 8;
        bf16v8 khf[4], klf[4];
        #pragma unroll
        for (int nt = 0; nt < 4; ++nt) {
          khf[nt] = *(const bf16v8*)&Kh_[(nt * 16 + l16) * 64 + co];
          klf[nt] = *(const bf16v8*)&Kl_[(nt * 16 + l16) * 64 + co];
        }
        #pragma unroll
        for (int sub = 0; sub < 2; ++sub)
          #pragma unroll
          for (int nt = 0; nt < 4; ++nt) {
            sacc[sub][nt] = MFMA16(khf[nt], qhf[sub][kk], sacc[sub][nt]);
            sacc[sub][nt] = MFMA16(klf[nt], qhf[sub][kk], sacc[sub][nt]);
            sacc[sub][nt] = MFMA16(khf[nt], qlf[sub][kk], sacc[sub][nt]);
          }
      }

      // ---- softmax per sub (all in-lane / in-register) ----
      // P packed directly into PV A-fragments: pa[kk] words = pkw[2kk].lo/hi,
      // pkw[2kk+1].lo/hi (lane-local; slot permutation absorbed by V read).
      pb8 pa[2][2];
      #pragma unroll
      for (int sub = 0; sub < 2; ++sub) {
        // causal mask: key = k0 + nt*16 + quad*4 + r ; qrow = qw0+sub*16+l16
        const int dq = (qw0 + sub * 16 + l16) - k0 - quad * 4;
        #pragma unroll
        for (int nt = 0; nt < 4; ++nt)
          #pragma unroll
          for (int r = 0; r < 4; ++r)
            if (nt * 16 + r > dq) sacc[sub][nt][r] = -1e30f;

        // in-lane row max over 16 values, then cross-quad reduce (uniform per l16 col)
        float mA = fmaxf(fmaxf(sacc[sub][0][0], sacc[sub][0][1]),
                         fmaxf(sacc[sub][0][2], sacc[sub][0][3]));
        float mB = fmaxf(fmaxf(sacc[sub][1][0], sacc[sub][1][1]),
                         fmaxf(sacc[sub][1][2], sacc[sub][1][3]));
        float mC = fmaxf(fmaxf(sacc[sub][2][0], sacc[sub][2][1]),
                         fmaxf(sacc[sub][2][2], sacc[sub][2][3]));
        float mD = fmaxf(fmaxf(sacc[sub][3][0], sacc[sub][3][1]),
                         fmaxf(sacc[sub][3][2], sacc[sub][3][3]));
        float mx = fmaxf(fmaxf(mA, mB), fmaxf(mC, mD));
        mx = fmaxf(mx, __shfl_xor(mx, 16, 64));
        mx = fmaxf(mx, __shfl_xor(mx, 32, 64));   // per-qrow max, uniform across quads

        const bool grow = __any(mx > mrow[sub]);  // wave-uniform
        const float mnew = grow ? fmaxf(mrow[sub], mx) : mrow[sub];

        // exp (log2 domain), pack to bf16 in registers; accumulate rounded sum
        float snt[4];
        #pragma unroll
        for (int nt = 0; nt < 4; ++nt) {
          bf16v4 t;
          float ss0 = 0.f, ss1 = 0.f;
          #pragma unroll
          for (int r = 0; r < 4; ++r) {
            float ev = __builtin_amdgcn_exp2f(sacc[sub][nt][r] - mnew);
            bf16 pb = (bf16)ev;
            t[r] = pb;
            if (r & 1) ss1 += (float)pb; else ss0 += (float)pb;
          }
          snt[nt] = ss0 + ss1;
          union { bf16v4 v; int w[2]; } u; u.v = t;
          pa[sub][nt >> 1].w[(nt & 1) * 2]     = u.w[0];
          pa[sub][nt >> 1].w[(nt & 1) * 2 + 1] = u.w[1];
        }
        float s = (snt[0] + snt[1]) + (snt[2] + snt[3]);
        s += __shfl_xor(s, 16, 64);
        s += __shfl_xor(s, 32, 64);               // per-qrow sum, uniform across quads

        if (grow) {
          const float alpha = __builtin_amdgcn_exp2f(mrow[sub] - mnew);  // l16 layout
          mrow[sub] = mnew;
          lsum[sub] = lsum[sub] * alpha + s;
          float abp[4];
          #pragma unroll
          for (int r = 0; r < 4; ++r)
            abp[r] = __shfl(alpha, quad * 20 + r, 64);   // alpha for qrow=quad*4+r
          #pragma unroll
          for (int dt = 0; dt < 4; ++dt)
            #pragma unroll
            for (int r = 0; r < 4; ++r)
              oacc[sub][dt][r] *= abp[r];
        } else {
          lsum[sub] += s;
        }
      }

      // ---- PV: zero-shuffle. A-slot (kk,quad,j) holds key
      // kk*32 + (j>>2)*16 + quad*4 + (j&3); V read matches with two b64
      // chunks at logical cols kk*32+quad*4 and +16 (swizzle-corrected). ----
      #pragma unroll
      for (int kk = 0; kk < 2; ++kk) {
        const int o_lo = (((kk * 4 +     (quad >> 1)) ^ xs) * 8) + (quad & 1) * 4;
        const int o_hi = (((kk * 4 + 2 + (quad >> 1)) ^ xs) * 8) + (quad & 1) * 4;
        #pragma unroll
        for (int dt = 0; dt < 4; ++dt) {
          const bf16* rowp = &Vt_[(dt * 16 + l16) * 64];
          union { bf16v8 v; bf16v4 h[2]; } vu;
          vu.h[0] = *(const bf16v4*)&rowp[o_lo];
          vu.h[1] = *(const bf16v4*)&rowp[o_hi];
          #pragma unroll
          for (int sub = 0; sub < 2; ++sub)
            oacc[sub][dt] = MFMA16(pa[sub][kk].v, vu.v, oacc[sub][dt]);
        }
      }
    }

    // epilogue: lsum (l16 layout) -> (quad,r) layout via shuffle, then divide
    #pragma unroll
    for (int sub = 0; sub < 2; ++sub) {
      float lrow[4];
      #pragma unroll
      for (int r = 0; r < 4; ++r)
        lrow[r] = __shfl(lsum[sub], quad * 20 + r, 64);
      #pragma unroll
      for (int dt = 0; dt < 4; ++dt)
        #pragma unroll
        for (int r = 0; r < 4; ++r) {
          int q = q0 + wid * 32 + sub * 16 + quad * 4 + r;
          int d = dt * 16 + l16;
          float val = oacc[sub][dt][r] / lrow[r];
          o[((size_t)(b * SEQ + q)) * EMB + h * HDIM + d] = (bf16)val;
        }
    }
  }
}

// ---------------- out projection (unchanged) ----------------

__launch_bounds__(256, 2)
__global__ void gemm_out_kernel(const bf16* __restrict__ oin, const bf16* __restrict__ wt,
                                float* __restrict__ out) {
  __shared__ __align__(16) bf16 As_[128 * 64];
  __shared__ __align__(16) bf16 Bs_[128 * 64];
  const int tid = threadIdx.x;
  const int lane = tid & 63, wid = tid >> 6;
  const int quad = lane >> 4, l16 = lane & 15;
  const int m0 = blockIdx.x * 128, n0 = blockIdx.y * 128;
  const int wm = (wid >> 1) * 64, wn = (wid & 1) * 64;
  f32v4 acc[4][4] = {};

  for (int kt = 0; kt < EMB / 64; ++kt) {
    __syncthreads();
    #pragma unroll
    for (int r = 0; r < 4; ++r) {
      int li = r * 256 + tid;
      int row = li >> 3, col = (li & 7) * 8;
      gload_lds16(oin + (size_t)(m0 + row) * EMB + kt * 64 + col, &As_[li * 8]);
      gload_lds16(wt  + (size_t)(n0 + row) * EMB + kt * 64 + col, &Bs_[li * 8]);
    }
    __syncthreads();
    #pragma unroll
    for (int kk = 0; kk < 2; ++kk) {
      bf16v8 af[4], bfr[4];
      #pragma unroll
      for (int i = 0; i < 4; ++i) {
        af[i]  = *(const bf16v8*)&As_[(wm + i * 16 + l16) * 64 + kk * 32 + quad * 8];
        bfr[i] = *(const bf16v8*)&Bs_[(wn + i * 16 + l16) * 64 + kk * 32 + quad * 8];
      }
      #pragma unroll
      for (int i = 0; i < 4; ++i)
        #pragma unroll
        for (int j = 0; j < 4; ++j)
          acc[i][j] = MFMA16(af[i], bfr[j], acc[i][j]);
    }
  }
  #pragma unroll
  for (int i = 0; i < 4; ++i)
    #pragma unroll
    for (int j = 0; j < 4; ++j)
      #pragma unroll
      for (int r = 0; r < 4; ++r) {
        int m = m0 + wm + i * 16 + quad * 4 + r;
        int n = n0 + wn + j * 16 + l16;
        out[(size_t)m * EMB + n] = acc[i][j][r];
      }
}

// ---------------- launch ----------------

extern "C" void kernel_launch(void* const* d_in, const int* in_sizes, int n_in,
                              void* d_out, int out_size, void* d_ws, size_t ws_size,
                              hipStream_t stream) {
  const float* x     = (const float*)d_in[0];
  const float* w_qkv = (const float*)d_in[1];
  const float* w_out = (const float*)d_in[2];
  float* out = (float*)d_out;
  char* ws = (char*)d_ws;

  const size_t SZ  = (size_t)MROWS * EMB * sizeof(bf16);   // 16.78 MB
  const size_t SZ8 = (size_t)MROWS * EMB;                  // 8.39 MB (i8 plane)
  size_t off = 0;
  float* sums = (float*)ws;            off = 256;
  char*  wq8  = (char*)(ws + off);     off += (size_t)NQKV * EMB;               // 3.1 MB
  bf16*  wo_t = (bf16*)(ws + off);     off += (size_t)EMB * EMB * sizeof(bf16); // 2.1 MB
  char*  xq1  = (char*)(ws + off);     off += SZ8;
  char*  xq2  = (char*)(ws + off);     off += SZ8;
  bf16*  qh   = (bf16*)(ws + off);     off += SZ;
  bf16*  ql   = (bf16*)(ws + off);     off += SZ;
  bf16*  kh   = (bf16*)(ws + off);     off += SZ;
  bf16*  kl   = (bf16*)(ws + off);     off += SZ;
  bf16*  vv   = (bf16*)(ws + off);     off += SZ;
  bf16*  vt   = (bf16*)xq1;   // x planes dead after gemm_qkv -> 16.8 MB spans xq1+xq2
  bf16*  ob   = vv;           // vv dead after transpose; attn writes ob
  (void)in_sizes; (void)n_in; (void)out_size; (void)ws_size;

  zero2_kernel<<<1, 2, 0, stream>>>(sums);
  abs_sum_kernel<<<256, 256, 0, stream>>>(w_qkv, NQKV * EMB, &sums[0]);
  abs_sum_kernel<<<256, 256, 0, stream>>>(w_out, EMB * EMB, &sums[1]);
  ternarize_i8_kernel<<<(NQKV * EMB) / 256, 256, 0, stream>>>(w_qkv, NQKV * EMB, &sums[0], wq8);
  ternarize_bf16_kernel<<<(EMB * EMB) / 256, 256, 0, stream>>>(w_out, EMB * EMB, &sums[1], wo_t);
  quant_x_kernel<<<(MROWS * EMB) / 256, 256, 0, stream>>>(x, xq1, xq2, MROWS * EMB);
  gemm_qkv_kernel<<<dim3(MROWS / 128, NQKV / 128), 256, 0, stream>>>(xq1, xq2, wq8, qh, ql, kh, kl, vv);
  transpose_v_kernel<<<dim3(SEQ / 64, BSZ * NHEAD), 256, 0, stream>>>(vv, vt);
  attn_kernel<<<dim3(8, BSZ * NHEAD), 256, 0, stream>>>(qh, ql, kh, kl, vt, ob);
  gemm_out_kernel<<<dim3(MROWS / 128, EMB / 128), 256, 0, stream>>>(ob, wo_t, out);
}

// Round 7
// 342.190 us; speedup vs baseline: 1.1156x; 1.1156x over previous
//
#include <hip/hip_runtime.h>
#include <hip/hip_bf16.h>

#define EMB   1024
#define NHEAD 16
#define HDIM  64
#define BSZ   4
#define SEQ   2048
#define MROWS (BSZ*SEQ)     // 8192
#define NQKV  (3*EMB)       // 3072

typedef __bf16 bf16;
typedef __bf16 bf16v8 __attribute__((ext_vector_type(8)));
typedef float  f32v4  __attribute__((ext_vector_type(4)));
typedef int    i32v4  __attribute__((ext_vector_type(4)));

#define MFMA16(a,b,c)  __builtin_amdgcn_mfma_f32_16x16x32_bf16((a),(b),(c),0,0,0)
#define MFMAI8(a,b,c)  __builtin_amdgcn_mfma_i32_16x16x64_i8((a),(b),(c),0,0,0)

__device__ __forceinline__ void gload_lds16(const void* g, void* l) {
  __builtin_amdgcn_global_load_lds((const __attribute__((address_space(1))) void*)g,
                                   (__attribute__((address_space(3))) void*)l,
                                   16, 0, 0);
}

// VALU (DPP) max-reduce over the 16-lane row: removes ds_swizzle from the DS pipe.
#define DPP_FMAX(x, ctrl) do {                                                     \
    int _t = __builtin_amdgcn_update_dpp(0, __float_as_int(x), (ctrl), 0xf, 0xf, true); \
    (x) = fmaxf((x), __int_as_float(_t)); } while (0)

// ---------------- scale reduction + ternarize + quantize ----------------

__global__ void zero2_kernel(float* p) { p[threadIdx.x] = 0.f; }

__global__ void abs_sum_kernel(const float* __restrict__ w, int n, float* out) {
  float s = 0.f;
  for (int i = blockIdx.x * blockDim.x + threadIdx.x; i < n; i += gridDim.x * blockDim.x)
    s += fabsf(w[i]);
  #pragma unroll
  for (int off = 32; off; off >>= 1) s += __shfl_down(s, off, 64);
  __shared__ float red[4];
  int lane = threadIdx.x & 63, wid = threadIdx.x >> 6;
  if (lane == 0) red[wid] = s;
  __syncthreads();
  if (threadIdx.x == 0) atomicAdd(out, red[0] + red[1] + red[2] + red[3]);
}

// ternary weights as i8 (exact)
__global__ void ternarize_i8_kernel(const float* __restrict__ w, int n,
                                    const float* __restrict__ sum, char* __restrict__ out) {
  int i = blockIdx.x * blockDim.x + threadIdx.x;
  if (i >= n) return;
  float scale = fmaxf(*sum / (float)n, 1e-8f);
  float t = rintf(w[i] / scale);          // RNE == jnp.round
  t = fmaxf(-1.f, fminf(1.f, t));
  out[i] = (char)(int)t;
}

// ternary weights as bf16 (for the bf16 out-projection GEMM)
__global__ void ternarize_bf16_kernel(const float* __restrict__ w, int n,
                                      const float* __restrict__ sum, bf16* __restrict__ out) {
  int i = blockIdx.x * blockDim.x + threadIdx.x;
  if (i >= n) return;
  float scale = fmaxf(*sum / (float)n, 1e-8f);
  float t = rintf(w[i] / scale);
  t = fmaxf(-1.f, fminf(1.f, t));
  out[i] = (bf16)t;
}

// x -> two i8 planes: x ~= p1/16 + p2/4096 (|err| <= 2.4e-4; exact i32 MFMA accum)
__global__ void quant_x_kernel(const float* __restrict__ x, char* __restrict__ p1,
                               char* __restrict__ p2, int n) {
  int i = blockIdx.x * blockDim.x + threadIdx.x;
  if (i >= n) return;
  float v = x[i];
  float q1 = fminf(fmaxf(rintf(v * 16.f), -127.f), 127.f);
  float r = v - q1 * 0.0625f;
  float q2 = fminf(fmaxf(rintf(r * 4096.f), -127.f), 127.f);
  p1[i] = (char)(int)q1;
  p2[i] = (char)(int)q2;
}

// ---------------- fused QKV GEMM, dual-plane i8 (unchanged) ----------------

__launch_bounds__(256, 2)
__global__ void gemm_qkv_kernel(const char* __restrict__ xq1, const char* __restrict__ xq2,
                                const char* __restrict__ w8,
                                bf16* __restrict__ qh, bf16* __restrict__ ql,
                                bf16* __restrict__ kh, bf16* __restrict__ kl,
                                bf16* __restrict__ vv) {
  __shared__ __align__(16) char A1[128 * 64];
  __shared__ __align__(16) char A2[128 * 64];
  __shared__ __align__(16) char Bs[128 * 64];
  const int tid = threadIdx.x;
  const int lane = tid & 63, wid = tid >> 6;
  const int quad = lane >> 4, l16 = lane & 15;
  const int m0 = blockIdx.x * 128, n0 = blockIdx.y * 128;
  const int wm = (wid >> 1) * 64, wn = (wid & 1) * 64;
  const int asw = (l16 >> 1) & 3;         // fragment-read swizzle
  i32v4 acc1[4][4] = {};
  i32v4 acc2[4][4] = {};

  for (int kt = 0; kt < EMB / 64; ++kt) {
    __syncthreads();
    #pragma unroll
    for (int r = 0; r < 2; ++r) {
      int li = r * 256 + tid;
      int row = li >> 2, cs = li & 3;
      int cg = cs ^ ((row >> 1) & 3);
      gload_lds16(xq1 + (size_t)(m0 + row) * EMB + kt * 64 + cg * 16, &A1[li * 16]);
      gload_lds16(xq2 + (size_t)(m0 + row) * EMB + kt * 64 + cg * 16, &A2[li * 16]);
      gload_lds16(w8  + (size_t)(n0 + row) * EMB + kt * 64 + cg * 16, &Bs[li * 16]);
    }
    __syncthreads();
    i32v4 af1[4], af2[4], bfr[4];
    #pragma unroll
    for (int i = 0; i < 4; ++i) {
      int arow = wm + i * 16 + l16;
      int off = arow * 64 + ((quad ^ asw) * 16);
      af1[i] = *(const i32v4*)&A1[off];
      af2[i] = *(const i32v4*)&A2[off];
      int brow = wn + i * 16 + l16;
      bfr[i] = *(const i32v4*)&Bs[brow * 64 + ((quad ^ asw) * 16)];
    }
    #pragma unroll
    for (int i = 0; i < 4; ++i)
      #pragma unroll
      for (int j = 0; j < 4; ++j) {
        acc1[i][j] = MFMAI8(af1[i], bfr[j], acc1[i][j]);
        acc2[i][j] = MFMAI8(af2[i], bfr[j], acc2[i][j]);
      }
  }
  const float S1 = 0.0625f, S2 = 1.f / 4096.f;
  const float QSCALE = 0.18033688011112042f;   // 0.125 * log2(e)
  #pragma unroll
  for (int i = 0; i < 4; ++i)
    #pragma unroll
    for (int j = 0; j < 4; ++j)
      #pragma unroll
      for (int r = 0; r < 4; ++r) {
        int m = m0 + wm + i * 16 + quad * 4 + r;
        int n = n0 + wn + j * 16 + l16;
        float c = (float)acc1[i][j][r] * S1 + (float)acc2[i][j][r] * S2;
        int b = m >> 11, t = m & (SEQ - 1);
        int region = n >> 10, c1 = n & 1023, h = c1 >> 6, d = c1 & 63;
        size_t idx = (((size_t)(b * NHEAD + h) * SEQ + t) << 6) + d;
        if (region == 0)      { float cs = c * QSCALE; bf16 hi = (bf16)cs; qh[idx] = hi; ql[idx] = (bf16)(cs - (float)hi); }
        else if (region == 1) { bf16 hi = (bf16)c; kh[idx] = hi; kl[idx] = (bf16)(c - (float)hi); }
        else                  { vv[idx] = (bf16)c; }
      }
}

// ---------------- V transpose: [B,H,T,D] -> [B,H,D,T] ----------------

__global__ void transpose_v_kernel(const bf16* __restrict__ v, bf16* __restrict__ vt) {
  __shared__ bf16 tile[64 * 72];
  const int tid = threadIdx.x;
  const int bh = blockIdx.y, t0 = blockIdx.x * 64;
  const size_t base = (size_t)bh * SEQ * HDIM;
  #pragma unroll
  for (int r = 0; r < 2; ++r) {
    int li = r * 256 + tid;
    int row = li >> 3, col = (li & 7) * 8;
    bf16v8 val = *(const bf16v8*)(v + base + (size_t)(t0 + row) * HDIM + col);
    #pragma unroll
    for (int j = 0; j < 8; ++j) tile[(col + j) * 72 + row] = val[j];
  }
  __syncthreads();
  #pragma unroll
  for (int r = 0; r < 2; ++r) {
    int li = r * 256 + tid;
    int drow = li >> 3, tcol = (li & 7) * 8;
    bf16v8 val;
    #pragma unroll
    for (int j = 0; j < 8; ++j) val[j] = tile[drow * 72 + tcol + j];
    *(bf16v8*)(vt + base + (size_t)drow * SEQ + t0 + tcol) = val;
  }
}

// ---------------- Flash attention ----------------
// R2-verified structure (130.7 us): 4 waves x 32 q-rows, DPP row-max,
// P via wave-private LDS slices, V shared across sub-tiles.
// ONLY change vs R2: grid mapping swapped -> bh = blockIdx.x, pair = blockIdx.y.
// Linear block id = bh + 64*pair, so the 8 pair-blocks of one head are
// 64 apart -> same XCD -> K/V of that head stays in one L2 (8x reuse).

__launch_bounds__(256, 2)
__global__ void attn_kernel(const bf16* __restrict__ qh, const bf16* __restrict__ ql,
                            const bf16* __restrict__ kh, const bf16* __restrict__ kl,
                            const bf16* __restrict__ vt, bf16* __restrict__ o) {
  __shared__ __align__(16) char smem[66560];
  // buf b at smem + b*24576: Kh [0,8K) | Kl [8K,16K) | Vt [16K,24K)
  bf16* Qh = (bf16*)smem;               // Q phase overlay (dead after frag read)
  bf16* Ql = (bf16*)(smem + 16384);
  bf16* Pw = (bf16*)(smem + 49152);     // 8 slices * 16*68*2 = 17408 B
  const int tid = threadIdx.x;
  const int lane = tid & 63, wid = tid >> 6;     // 4 waves
  const int quad = lane >> 4, l16 = lane & 15;
  const int xs = l16 & 7;
  const int pair = blockIdx.y;          // 0..7  (swapped: y is pair now)
  const int bh = blockIdx.x;            // 0..63 (swapped: x is head now)
  const size_t base = (size_t)bh * SEQ * HDIM;

  auto stage_kv = [&](char* dst, int k0) {
    #pragma unroll
    for (int r = 0; r < 2; ++r) {
      int li = r * 256 + tid;
      int srow = li >> 3, scg = (li & 7) ^ (srow & 7);
      gload_lds16(kh + base + (size_t)(k0 + srow) * HDIM + scg * 8, (bf16*)dst + (size_t)li * 8);
      gload_lds16(kl + base + (size_t)(k0 + srow) * HDIM + scg * 8, (bf16*)(dst + 8192) + (size_t)li * 8);
      gload_lds16(vt + base + (size_t)srow * SEQ + k0 + scg * 8,    (bf16*)(dst + 16384) + (size_t)li * 8);
    }
  };

  bf16v8 ones_f;
  {
    bf16 v1 = (l16 == 0) ? (bf16)1.0f : (bf16)0.0f;
    #pragma unroll
    for (int j = 0; j < 8; ++j) ones_f[j] = v1;
  }
  const int b = bh >> 4, h = bh & 15;

  for (int phase = 0; phase < 2; ++phase) {
    const int qt = phase ? (7 - pair) : (8 + pair);
    const int q0 = qt * 128;

    __syncthreads();                    // prior phase's LDS readers done
    // stage Q (hi+lo), swizzled
    #pragma unroll
    for (int r = 0; r < 4; ++r) {
      int li = r * 256 + tid;
      int row = li >> 3, cg = (li & 7) ^ (row & 7);
      gload_lds16(qh + base + (size_t)(q0 + row) * HDIM + cg * 8, &Qh[li * 8]);
      gload_lds16(ql + base + (size_t)(q0 + row) * HDIM + cg * 8, &Ql[li * 8]);
    }
    __syncthreads();
    bf16v8 qhf[2][2], qlf[2][2];
    #pragma unroll
    for (int sub = 0; sub < 2; ++sub)
      #pragma unroll
      for (int kk = 0; kk < 2; ++kk) {
        int off = (wid * 32 + sub * 16 + l16) * 64 + (((kk << 2) | quad) ^ xs) * 8;
        qhf[sub][kk] = *(const bf16v8*)&Qh[off];
        qlf[sub][kk] = *(const bf16v8*)&Ql[off];
      }
    __syncthreads();                    // all waves hold Q frags; bufs free

    f32v4 oacc[2][4] = {};
    f32v4 lacc[2] = {};
    float mrow[2][4];
    #pragma unroll
    for (int s = 0; s < 2; ++s)
      #pragma unroll
      for (int r = 0; r < 4; ++r) mrow[s][r] = -1e30f;

    const int qw0 = q0 + wid * 32;
    const int qrow_hi = qw0 + 31;       // wave-uniform causal limit (covers both subs)
    const int ntiles = 2 * qt + 2;

    stage_kv(smem, 0);                  // preload tile 0 -> buf0 (cold drain once)

    for (int ktile = 0; ktile < ntiles; ++ktile) {
      char* cb = smem + (size_t)((ktile & 1) * 24576);
      char* nb = smem + (size_t)(((ktile + 1) & 1) * 24576);
      __syncthreads();                  // tile ktile staged (all waves); prev buf free
      if (ktile + 1 < ntiles) stage_kv(nb, (ktile + 1) * 64);   // prefetch, in flight
      const int k0 = ktile * 64;
      if (k0 > qrow_hi) continue;       // fully-masked tile for this wave

      bf16* Kh_ = (bf16*)cb;
      bf16* Kl_ = (bf16*)(cb + 8192);
      bf16* Vt_ = (bf16*)(cb + 16384);

      // ---- QK^T: K fragments read once, reused by both sub-tiles ----
      f32v4 sacc[2][4] = {};
      #pragma unroll
      for (int kk = 0; kk < 2; ++kk) {
        const int co = (((kk << 2) | quad) ^ xs) * 8;
        bf16v8 khf[4], klf[4];
        #pragma unroll
        for (int nt = 0; nt < 4; ++nt) {
          khf[nt] = *(const bf16v8*)&Kh_[(nt * 16 + l16) * 64 + co];
          klf[nt] = *(const bf16v8*)&Kl_[(nt * 16 + l16) * 64 + co];
        }
        #pragma unroll
        for (int sub = 0; sub < 2; ++sub)
          #pragma unroll
          for (int nt = 0; nt < 4; ++nt) {
            sacc[sub][nt] = MFMA16(qhf[sub][kk], khf[nt], sacc[sub][nt]);
            sacc[sub][nt] = MFMA16(qhf[sub][kk], klf[nt], sacc[sub][nt]);
            sacc[sub][nt] = MFMA16(qlf[sub][kk], khf[nt], sacc[sub][nt]);
          }
      }

      // ---- softmax per sub-tile (scores already in log2 domain) ----
      #pragma unroll
      for (int sub = 0; sub < 2; ++sub) {
        if (k0 > qw0 + sub * 16 + 15) continue;   // sub fully masked (only sub0 can hit)
        const int qrow_base = qw0 + sub * 16 + quad * 4;
        #pragma unroll
        for (int nt = 0; nt < 4; ++nt) {
          int key = k0 + nt * 16 + l16;
          #pragma unroll
          for (int r = 0; r < 4; ++r)
            if (key > qrow_base + r) sacc[sub][nt][r] = -1e30f;
        }
        float alpha[4];
        #pragma unroll
        for (int r = 0; r < 4; ++r) {
          float mx = fmaxf(fmaxf(sacc[sub][0][r], sacc[sub][1][r]),
                           fmaxf(sacc[sub][2][r], sacc[sub][3][r]));
          DPP_FMAX(mx, 0x128);          // row_ror:8
          DPP_FMAX(mx, 0x124);          // row_ror:4
          DPP_FMAX(mx, 0x122);          // row_ror:2
          DPP_FMAX(mx, 0x121);          // row_ror:1
          float mnew = fmaxf(mrow[sub][r], mx);
          alpha[r] = __builtin_amdgcn_exp2f(mrow[sub][r] - mnew);
          mrow[sub][r] = mnew;
        }
        bf16* pwave = Pw + (wid * 2 + sub) * (16 * 68);
        #pragma unroll
        for (int nt = 0; nt < 4; ++nt)
          #pragma unroll
          for (int r = 0; r < 4; ++r)
            pwave[(quad * 4 + r) * 68 + nt * 16 + l16] =
                (bf16)__builtin_amdgcn_exp2f(sacc[sub][nt][r] - mrow[sub][r]);
        #pragma unroll
        for (int r = 0; r < 4; ++r) {
          lacc[sub][r] *= alpha[r];
          #pragma unroll
          for (int dt = 0; dt < 4; ++dt) oacc[sub][dt][r] *= alpha[r];
        }
      }

      // ---- PV + row-sum: V fragments read once, reused by both sub-tiles ----
      #pragma unroll
      for (int kk = 0; kk < 2; ++kk) {
        const int co = (((kk << 2) | quad) ^ xs) * 8;
        bf16v8 vf[4];
        #pragma unroll
        for (int dt = 0; dt < 4; ++dt)
          vf[dt] = *(const bf16v8*)&Vt_[(dt * 16 + l16) * 64 + co];
        #pragma unroll
        for (int sub = 0; sub < 2; ++sub) {
          if (k0 > qw0 + sub * 16 + 15) continue;
          bf16v8 pf = *(const bf16v8*)&Pw[(wid * 2 + sub) * (16 * 68) + l16 * 68 + kk * 32 + quad * 8];
          lacc[sub] = MFMA16(pf, ones_f, lacc[sub]);
          #pragma unroll
          for (int dt = 0; dt < 4; ++dt)
            oacc[sub][dt] = MFMA16(pf, vf[dt], oacc[sub][dt]);
        }
      }
    }

    // row-sum lives in column 0 (lane l16==0 of each quad) -> broadcast
    #pragma unroll
    for (int sub = 0; sub < 2; ++sub) {
      float lrow[4];
      #pragma unroll
      for (int r = 0; r < 4; ++r) lrow[r] = __shfl(lacc[sub][r], lane & 48, 64);
      #pragma unroll
      for (int dt = 0; dt < 4; ++dt)
        #pragma unroll
        for (int r = 0; r < 4; ++r) {
          int q = q0 + wid * 32 + sub * 16 + quad * 4 + r;
          int d = dt * 16 + l16;
          float val = oacc[sub][dt][r] / lrow[r];
          o[((size_t)(b * SEQ + q)) * EMB + h * HDIM + d] = (bf16)val;
        }
    }
  }
}

// ---------------- out projection (unchanged) ----------------

__launch_bounds__(256, 2)
__global__ void gemm_out_kernel(const bf16* __restrict__ oin, const bf16* __restrict__ wt,
                                float* __restrict__ out) {
  __shared__ __align__(16) bf16 As_[128 * 64];
  __shared__ __align__(16) bf16 Bs_[128 * 64];
  const int tid = threadIdx.x;
  const int lane = tid & 63, wid = tid >> 6;
  const int quad = lane >> 4, l16 = lane & 15;
  const int m0 = blockIdx.x * 128, n0 = blockIdx.y * 128;
  const int wm = (wid >> 1) * 64, wn = (wid & 1) * 64;
  f32v4 acc[4][4] = {};

  for (int kt = 0; kt < EMB / 64; ++kt) {
    __syncthreads();
    #pragma unroll
    for (int r = 0; r < 4; ++r) {
      int li = r * 256 + tid;
      int row = li >> 3, col = (li & 7) * 8;
      gload_lds16(oin + (size_t)(m0 + row) * EMB + kt * 64 + col, &As_[li * 8]);
      gload_lds16(wt  + (size_t)(n0 + row) * EMB + kt * 64 + col, &Bs_[li * 8]);
    }
    __syncthreads();
    #pragma unroll
    for (int kk = 0; kk < 2; ++kk) {
      bf16v8 af[4], bfr[4];
      #pragma unroll
      for (int i = 0; i < 4; ++i) {
        af[i]  = *(const bf16v8*)&As_[(wm + i * 16 + l16) * 64 + kk * 32 + quad * 8];
        bfr[i] = *(const bf16v8*)&Bs_[(wn + i * 16 + l16) * 64 + kk * 32 + quad * 8];
      }
      #pragma unroll
      for (int i = 0; i < 4; ++i)
        #pragma unroll
        for (int j = 0; j < 4; ++j)
          acc[i][j] = MFMA16(af[i], bfr[j], acc[i][j]);
    }
  }
  #pragma unroll
  for (int i = 0; i < 4; ++i)
    #pragma unroll
    for (int j = 0; j < 4; ++j)
      #pragma unroll
      for (int r = 0; r < 4; ++r) {
        int m = m0 + wm + i * 16 + quad * 4 + r;
        int n = n0 + wn + j * 16 + l16;
        out[(size_t)m * EMB + n] = acc[i][j][r];
      }
}

// ---------------- launch ----------------

extern "C" void kernel_launch(void* const* d_in, const int* in_sizes, int n_in,
                              void* d_out, int out_size, void* d_ws, size_t ws_size,
                              hipStream_t stream) {
  const float* x     = (const float*)d_in[0];
  const float* w_qkv = (const float*)d_in[1];
  const float* w_out = (const float*)d_in[2];
  float* out = (float*)d_out;
  char* ws = (char*)d_ws;

  const size_t SZ  = (size_t)MROWS * EMB * sizeof(bf16);   // 16.78 MB
  const size_t SZ8 = (size_t)MROWS * EMB;                  // 8.39 MB (i8 plane)
  size_t off = 0;
  float* sums = (float*)ws;            off = 256;
  char*  wq8  = (char*)(ws + off);     off += (size_t)NQKV * EMB;               // 3.1 MB
  bf16*  wo_t = (bf16*)(ws + off);     off += (size_t)EMB * EMB * sizeof(bf16); // 2.1 MB
  char*  xq1  = (char*)(ws + off);     off += SZ8;
  char*  xq2  = (char*)(ws + off);     off += SZ8;
  bf16*  qh   = (bf16*)(ws + off);     off += SZ;
  bf16*  ql   = (bf16*)(ws + off);     off += SZ;
  bf16*  kh   = (bf16*)(ws + off);     off += SZ;
  bf16*  kl   = (bf16*)(ws + off);     off += SZ;
  bf16*  vv   = (bf16*)(ws + off);     off += SZ;
  bf16*  vt   = (bf16*)xq1;   // x planes dead after gemm_qkv -> 16.8 MB spans xq1+xq2
  bf16*  ob   = vv;           // vv dead after transpose; attn writes ob
  (void)in_sizes; (void)n_in; (void)out_size; (void)ws_size;

  zero2_kernel<<<1, 2, 0, stream>>>(sums);
  abs_sum_kernel<<<256, 256, 0, stream>>>(w_qkv, NQKV * EMB, &sums[0]);
  abs_sum_kernel<<<256, 256, 0, stream>>>(w_out, EMB * EMB, &sums[1]);
  ternarize_i8_kernel<<<(NQKV * EMB) / 256, 256, 0, stream>>>(w_qkv, NQKV * EMB, &sums[0], wq8);
  ternarize_bf16_kernel<<<(EMB * EMB) / 256, 256, 0, stream>>>(w_out, EMB * EMB, &sums[1], wo_t);
  quant_x_kernel<<<(MROWS * EMB) / 256, 256, 0, stream>>>(x, xq1, xq2, MROWS * EMB);
  gemm_qkv_kernel<<<dim3(MROWS / 128, NQKV / 128), 256, 0, stream>>>(xq1, xq2, wq8, qh, ql, kh, kl, vv);
  transpose_v_kernel<<<dim3(SEQ / 64, BSZ * NHEAD), 256, 0, stream>>>(vv, vt);
  attn_kernel<<<dim3(BSZ * NHEAD, 8), 256, 0, stream>>>(qh, ql, kh, kl, vt, ob);
  gemm_out_kernel<<<dim3(MROWS / 128, EMB / 128), 256, 0, stream>>>(ob, wo_t, out);
}

// Round 8
// 336.755 us; speedup vs baseline: 1.1336x; 1.0161x over previous
//
#include <hip/hip_runtime.h>
#include <hip/hip_bf16.h>

#define EMB   1024
#define NHEAD 16
#define HDIM  64
#define BSZ   4
#define SEQ   2048
#define MROWS (BSZ*SEQ)     // 8192
#define NQKV  (3*EMB)       // 3072

typedef __bf16 bf16;
typedef __bf16 bf16v4 __attribute__((ext_vector_type(4)));
typedef __bf16 bf16v8 __attribute__((ext_vector_type(8)));
typedef float  f32v4  __attribute__((ext_vector_type(4)));
typedef int    i32v4  __attribute__((ext_vector_type(4)));

#define MFMA16(a,b,c)  __builtin_amdgcn_mfma_f32_16x16x32_bf16((a),(b),(c),0,0,0)
#define MFMAI8(a,b,c)  __builtin_amdgcn_mfma_i32_16x16x64_i8((a),(b),(c),0,0,0)

__device__ __forceinline__ void gload_lds16(const void* g, void* l) {
  __builtin_amdgcn_global_load_lds((const __attribute__((address_space(1))) void*)g,
                                   (__attribute__((address_space(3))) void*)l,
                                   16, 0, 0);
}

// VALU (DPP) max-reduce over the 16-lane row: removes ds_swizzle from the DS pipe.
#define DPP_FMAX(x, ctrl) do {                                                     \
    int _t = __builtin_amdgcn_update_dpp(0, __float_as_int(x), (ctrl), 0xf, 0xf, true); \
    (x) = fmaxf((x), __int_as_float(_t)); } while (0)

// ---------------- scale reduction + ternarize + quantize ----------------

__global__ void zero2_kernel(float* p) { p[threadIdx.x] = 0.f; }

__global__ void abs_sum_kernel(const float* __restrict__ w, int n, float* out) {
  float s = 0.f;
  for (int i = blockIdx.x * blockDim.x + threadIdx.x; i < n; i += gridDim.x * blockDim.x)
    s += fabsf(w[i]);
  #pragma unroll
  for (int off = 32; off; off >>= 1) s += __shfl_down(s, off, 64);
  __shared__ float red[4];
  int lane = threadIdx.x & 63, wid = threadIdx.x >> 6;
  if (lane == 0) red[wid] = s;
  __syncthreads();
  if (threadIdx.x == 0) atomicAdd(out, red[0] + red[1] + red[2] + red[3]);
}

// ternary weights as i8 (exact)
__global__ void ternarize_i8_kernel(const float* __restrict__ w, int n,
                                    const float* __restrict__ sum, char* __restrict__ out) {
  int i = blockIdx.x * blockDim.x + threadIdx.x;
  if (i >= n) return;
  float scale = fmaxf(*sum / (float)n, 1e-8f);
  float t = rintf(w[i] / scale);          // RNE == jnp.round
  t = fmaxf(-1.f, fminf(1.f, t));
  out[i] = (char)(int)t;
}

// ternary weights as bf16 (for the bf16 out-projection GEMM)
__global__ void ternarize_bf16_kernel(const float* __restrict__ w, int n,
                                      const float* __restrict__ sum, bf16* __restrict__ out) {
  int i = blockIdx.x * blockDim.x + threadIdx.x;
  if (i >= n) return;
  float scale = fmaxf(*sum / (float)n, 1e-8f);
  float t = rintf(w[i] / scale);
  t = fmaxf(-1.f, fminf(1.f, t));
  out[i] = (bf16)t;
}

// x -> two i8 planes: x ~= p1/16 + p2/4096 (|err| <= 2.4e-4; exact i32 MFMA accum)
__global__ void quant_x_kernel(const float* __restrict__ x, char* __restrict__ p1,
                               char* __restrict__ p2, int n) {
  int i = blockIdx.x * blockDim.x + threadIdx.x;
  if (i >= n) return;
  float v = x[i];
  float q1 = fminf(fmaxf(rintf(v * 16.f), -127.f), 127.f);
  float r = v - q1 * 0.0625f;
  float q2 = fminf(fmaxf(rintf(r * 4096.f), -127.f), 127.f);
  p1[i] = (char)(int)q1;
  p2[i] = (char)(int)q2;
}

// ---------------- fused QKV GEMM, dual-plane i8 ----------------
// V-transpose fused into the epilogue: region 2 writes vt[bh][d][t] directly
// (4 consecutive t per (i,j) -> one packed bf16v4 store). vv buffer and the
// transpose_v kernel are gone. Region branch is block-uniform (boundaries at
// multiples of 128).

__launch_bounds__(256, 2)
__global__ void gemm_qkv_kernel(const char* __restrict__ xq1, const char* __restrict__ xq2,
                                const char* __restrict__ w8,
                                bf16* __restrict__ qh, bf16* __restrict__ ql,
                                bf16* __restrict__ kh, bf16* __restrict__ kl,
                                bf16* __restrict__ vt) {
  __shared__ __align__(16) char A1[128 * 64];
  __shared__ __align__(16) char A2[128 * 64];
  __shared__ __align__(16) char Bs[128 * 64];
  const int tid = threadIdx.x;
  const int lane = tid & 63, wid = tid >> 6;
  const int quad = lane >> 4, l16 = lane & 15;
  const int m0 = blockIdx.x * 128, n0 = blockIdx.y * 128;
  const int wm = (wid >> 1) * 64, wn = (wid & 1) * 64;
  const int asw = (l16 >> 1) & 3;         // fragment-read swizzle
  i32v4 acc1[4][4] = {};
  i32v4 acc2[4][4] = {};

  for (int kt = 0; kt < EMB / 64; ++kt) {
    __syncthreads();
    #pragma unroll
    for (int r = 0; r < 2; ++r) {
      int li = r * 256 + tid;
      int row = li >> 2, cs = li & 3;
      int cg = cs ^ ((row >> 1) & 3);
      gload_lds16(xq1 + (size_t)(m0 + row) * EMB + kt * 64 + cg * 16, &A1[li * 16]);
      gload_lds16(xq2 + (size_t)(m0 + row) * EMB + kt * 64 + cg * 16, &A2[li * 16]);
      gload_lds16(w8  + (size_t)(n0 + row) * EMB + kt * 64 + cg * 16, &Bs[li * 16]);
    }
    __syncthreads();
    i32v4 af1[4], af2[4], bfr[4];
    #pragma unroll
    for (int i = 0; i < 4; ++i) {
      int arow = wm + i * 16 + l16;
      int off = arow * 64 + ((quad ^ asw) * 16);
      af1[i] = *(const i32v4*)&A1[off];
      af2[i] = *(const i32v4*)&A2[off];
      int brow = wn + i * 16 + l16;
      bfr[i] = *(const i32v4*)&Bs[brow * 64 + ((quad ^ asw) * 16)];
    }
    #pragma unroll
    for (int i = 0; i < 4; ++i)
      #pragma unroll
      for (int j = 0; j < 4; ++j) {
        acc1[i][j] = MFMAI8(af1[i], bfr[j], acc1[i][j]);
        acc2[i][j] = MFMAI8(af2[i], bfr[j], acc2[i][j]);
      }
  }
  const float S1 = 0.0625f, S2 = 1.f / 4096.f;
  const float QSCALE = 0.18033688011112042f;   // 0.125 * log2(e)
  #pragma unroll
  for (int i = 0; i < 4; ++i)
    #pragma unroll
    for (int j = 0; j < 4; ++j) {
      const int n = n0 + wn + j * 16 + l16;
      const int region = n >> 10, c1 = n & 1023, h = c1 >> 6, d = c1 & 63;
      const int m_b = m0 + wm + i * 16 + quad * 4;
      float c[4];
      #pragma unroll
      for (int r = 0; r < 4; ++r)
        c[r] = (float)acc1[i][j][r] * S1 + (float)acc2[i][j][r] * S2;
      if (region == 0) {
        #pragma unroll
        for (int r = 0; r < 4; ++r) {
          int m = m_b + r;
          int b = m >> 11, t = m & (SEQ - 1);
          size_t idx = (((size_t)(b * NHEAD + h) * SEQ + t) << 6) + d;
          float cs = c[r] * QSCALE;
          bf16 hi = (bf16)cs;
          qh[idx] = hi; ql[idx] = (bf16)(cs - (float)hi);
        }
      } else if (region == 1) {
        #pragma unroll
        for (int r = 0; r < 4; ++r) {
          int m = m_b + r;
          int b = m >> 11, t = m & (SEQ - 1);
          size_t idx = (((size_t)(b * NHEAD + h) * SEQ + t) << 6) + d;
          bf16 hi = (bf16)c[r];
          kh[idx] = hi; kl[idx] = (bf16)(c[r] - (float)hi);
        }
      } else {
        // V: write transposed [bh][d][t]; 4 consecutive t -> one 8B store
        bf16v4 pk;
        #pragma unroll
        for (int r = 0; r < 4; ++r) pk[r] = (bf16)c[r];
        int b = m_b >> 11, t = m_b & (SEQ - 1);
        *(bf16v4*)&vt[((size_t)(b * NHEAD + h) * HDIM + d) * SEQ + t] = pk;
      }
    }
}

// ---------------- Flash attention ----------------
// R2-verified structure + grid (130.7 us measured): 4 waves x 32 q-rows,
// DPP row-max, P via wave-private LDS slices, V shared across sub-tiles,
// pair-major grid dim3(8, BH). (R7's bh-major XCD swizzle cut FETCH 3.7x but
// measured +5 us -> kernel is not memory-bound; keep the faster mapping.)

__launch_bounds__(256, 2)
__global__ void attn_kernel(const bf16* __restrict__ qh, const bf16* __restrict__ ql,
                            const bf16* __restrict__ kh, const bf16* __restrict__ kl,
                            const bf16* __restrict__ vt, bf16* __restrict__ o) {
  __shared__ __align__(16) char smem[66560];
  // buf b at smem + b*24576: Kh [0,8K) | Kl [8K,16K) | Vt [16K,24K)
  bf16* Qh = (bf16*)smem;               // Q phase overlay (dead after frag read)
  bf16* Ql = (bf16*)(smem + 16384);
  bf16* Pw = (bf16*)(smem + 49152);     // 8 slices * 16*68*2 = 17408 B
  const int tid = threadIdx.x;
  const int lane = tid & 63, wid = tid >> 6;     // 4 waves
  const int quad = lane >> 4, l16 = lane & 15;
  const int xs = l16 & 7;
  const int pair = blockIdx.x;          // 0..7
  const int bh = blockIdx.y;
  const size_t base = (size_t)bh * SEQ * HDIM;

  auto stage_kv = [&](char* dst, int k0) {
    #pragma unroll
    for (int r = 0; r < 2; ++r) {
      int li = r * 256 + tid;
      int srow = li >> 3, scg = (li & 7) ^ (srow & 7);
      gload_lds16(kh + base + (size_t)(k0 + srow) * HDIM + scg * 8, (bf16*)dst + (size_t)li * 8);
      gload_lds16(kl + base + (size_t)(k0 + srow) * HDIM + scg * 8, (bf16*)(dst + 8192) + (size_t)li * 8);
      gload_lds16(vt + base + (size_t)srow * SEQ + k0 + scg * 8,    (bf16*)(dst + 16384) + (size_t)li * 8);
    }
  };

  bf16v8 ones_f;
  {
    bf16 v1 = (l16 == 0) ? (bf16)1.0f : (bf16)0.0f;
    #pragma unroll
    for (int j = 0; j < 8; ++j) ones_f[j] = v1;
  }
  const int b = bh >> 4, h = bh & 15;

  for (int phase = 0; phase < 2; ++phase) {
    const int qt = phase ? (7 - pair) : (8 + pair);
    const int q0 = qt * 128;

    __syncthreads();                    // prior phase's LDS readers done
    // stage Q (hi+lo), swizzled
    #pragma unroll
    for (int r = 0; r < 4; ++r) {
      int li = r * 256 + tid;
      int row = li >> 3, cg = (li & 7) ^ (row & 7);
      gload_lds16(qh + base + (size_t)(q0 + row) * HDIM + cg * 8, &Qh[li * 8]);
      gload_lds16(ql + base + (size_t)(q0 + row) * HDIM + cg * 8, &Ql[li * 8]);
    }
    __syncthreads();
    bf16v8 qhf[2][2], qlf[2][2];
    #pragma unroll
    for (int sub = 0; sub < 2; ++sub)
      #pragma unroll
      for (int kk = 0; kk < 2; ++kk) {
        int off = (wid * 32 + sub * 16 + l16) * 64 + (((kk << 2) | quad) ^ xs) * 8;
        qhf[sub][kk] = *(const bf16v8*)&Qh[off];
        qlf[sub][kk] = *(const bf16v8*)&Ql[off];
      }
    __syncthreads();                    // all waves hold Q frags; bufs free

    f32v4 oacc[2][4] = {};
    f32v4 lacc[2] = {};
    float mrow[2][4];
    #pragma unroll
    for (int s = 0; s < 2; ++s)
      #pragma unroll
      for (int r = 0; r < 4; ++r) mrow[s][r] = -1e30f;

    const int qw0 = q0 + wid * 32;
    const int qrow_hi = qw0 + 31;       // wave-uniform causal limit (covers both subs)
    const int ntiles = 2 * qt + 2;

    stage_kv(smem, 0);                  // preload tile 0 -> buf0 (cold drain once)

    for (int ktile = 0; ktile < ntiles; ++ktile) {
      char* cb = smem + (size_t)((ktile & 1) * 24576);
      char* nb = smem + (size_t)(((ktile + 1) & 1) * 24576);
      __syncthreads();                  // tile ktile staged (all waves); prev buf free
      if (ktile + 1 < ntiles) stage_kv(nb, (ktile + 1) * 64);   // prefetch, in flight
      const int k0 = ktile * 64;
      if (k0 > qrow_hi) continue;       // fully-masked tile for this wave

      bf16* Kh_ = (bf16*)cb;
      bf16* Kl_ = (bf16*)(cb + 8192);
      bf16* Vt_ = (bf16*)(cb + 16384);

      // ---- QK^T: K fragments read once, reused by both sub-tiles ----
      f32v4 sacc[2][4] = {};
      #pragma unroll
      for (int kk = 0; kk < 2; ++kk) {
        const int co = (((kk << 2) | quad) ^ xs) * 8;
        bf16v8 khf[4], klf[4];
        #pragma unroll
        for (int nt = 0; nt < 4; ++nt) {
          khf[nt] = *(const bf16v8*)&Kh_[(nt * 16 + l16) * 64 + co];
          klf[nt] = *(const bf16v8*)&Kl_[(nt * 16 + l16) * 64 + co];
        }
        #pragma unroll
        for (int sub = 0; sub < 2; ++sub)
          #pragma unroll
          for (int nt = 0; nt < 4; ++nt) {
            sacc[sub][nt] = MFMA16(qhf[sub][kk], khf[nt], sacc[sub][nt]);
            sacc[sub][nt] = MFMA16(qhf[sub][kk], klf[nt], sacc[sub][nt]);
            sacc[sub][nt] = MFMA16(qlf[sub][kk], khf[nt], sacc[sub][nt]);
          }
      }

      // ---- softmax per sub-tile (scores already in log2 domain) ----
      #pragma unroll
      for (int sub = 0; sub < 2; ++sub) {
        if (k0 > qw0 + sub * 16 + 15) continue;   // sub fully masked (only sub0 can hit)
        const int qrow_base = qw0 + sub * 16 + quad * 4;
        #pragma unroll
        for (int nt = 0; nt < 4; ++nt) {
          int key = k0 + nt * 16 + l16;
          #pragma unroll
          for (int r = 0; r < 4; ++r)
            if (key > qrow_base + r) sacc[sub][nt][r] = -1e30f;
        }
        float alpha[4];
        #pragma unroll
        for (int r = 0; r < 4; ++r) {
          float mx = fmaxf(fmaxf(sacc[sub][0][r], sacc[sub][1][r]),
                           fmaxf(sacc[sub][2][r], sacc[sub][3][r]));
          DPP_FMAX(mx, 0x128);          // row_ror:8
          DPP_FMAX(mx, 0x124);          // row_ror:4
          DPP_FMAX(mx, 0x122);          // row_ror:2
          DPP_FMAX(mx, 0x121);          // row_ror:1
          float mnew = fmaxf(mrow[sub][r], mx);
          alpha[r] = __builtin_amdgcn_exp2f(mrow[sub][r] - mnew);
          mrow[sub][r] = mnew;
        }
        bf16* pwave = Pw + (wid * 2 + sub) * (16 * 68);
        #pragma unroll
        for (int nt = 0; nt < 4; ++nt)
          #pragma unroll
          for (int r = 0; r < 4; ++r)
            pwave[(quad * 4 + r) * 68 + nt * 16 + l16] =
                (bf16)__builtin_amdgcn_exp2f(sacc[sub][nt][r] - mrow[sub][r]);
        #pragma unroll
        for (int r = 0; r < 4; ++r) {
          lacc[sub][r] *= alpha[r];
          #pragma unroll
          for (int dt = 0; dt < 4; ++dt) oacc[sub][dt][r] *= alpha[r];
        }
      }

      // ---- PV + row-sum: V fragments read once, reused by both sub-tiles ----
      #pragma unroll
      for (int kk = 0; kk < 2; ++kk) {
        const int co = (((kk << 2) | quad) ^ xs) * 8;
        bf16v8 vf[4];
        #pragma unroll
        for (int dt = 0; dt < 4; ++dt)
          vf[dt] = *(const bf16v8*)&Vt_[(dt * 16 + l16) * 64 + co];
        #pragma unroll
        for (int sub = 0; sub < 2; ++sub) {
          if (k0 > qw0 + sub * 16 + 15) continue;
          bf16v8 pf = *(const bf16v8*)&Pw[(wid * 2 + sub) * (16 * 68) + l16 * 68 + kk * 32 + quad * 8];
          lacc[sub] = MFMA16(pf, ones_f, lacc[sub]);
          #pragma unroll
          for (int dt = 0; dt < 4; ++dt)
            oacc[sub][dt] = MFMA16(pf, vf[dt], oacc[sub][dt]);
        }
      }
    }

    // row-sum lives in column 0 (lane l16==0 of each quad) -> broadcast
    #pragma unroll
    for (int sub = 0; sub < 2; ++sub) {
      float lrow[4];
      #pragma unroll
      for (int r = 0; r < 4; ++r) lrow[r] = __shfl(lacc[sub][r], lane & 48, 64);
      #pragma unroll
      for (int dt = 0; dt < 4; ++dt)
        #pragma unroll
        for (int r = 0; r < 4; ++r) {
          int q = q0 + wid * 32 + sub * 16 + quad * 4 + r;
          int d = dt * 16 + l16;
          float val = oacc[sub][dt][r] / lrow[r];
          o[((size_t)(b * SEQ + q)) * EMB + h * HDIM + d] = (bf16)val;
        }
    }
  }
}

// ---------------- out projection (unchanged) ----------------

__launch_bounds__(256, 2)
__global__ void gemm_out_kernel(const bf16* __restrict__ oin, const bf16* __restrict__ wt,
                                float* __restrict__ out) {
  __shared__ __align__(16) bf16 As_[128 * 64];
  __shared__ __align__(16) bf16 Bs_[128 * 64];
  const int tid = threadIdx.x;
  const int lane = tid & 63, wid = tid >> 6;
  const int quad = lane >> 4, l16 = lane & 15;
  const int m0 = blockIdx.x * 128, n0 = blockIdx.y * 128;
  const int wm = (wid >> 1) * 64, wn = (wid & 1) * 64;
  f32v4 acc[4][4] = {};

  for (int kt = 0; kt < EMB / 64; ++kt) {
    __syncthreads();
    #pragma unroll
    for (int r = 0; r < 4; ++r) {
      int li = r * 256 + tid;
      int row = li >> 3, col = (li & 7) * 8;
      gload_lds16(oin + (size_t)(m0 + row) * EMB + kt * 64 + col, &As_[li * 8]);
      gload_lds16(wt  + (size_t)(n0 + row) * EMB + kt * 64 + col, &Bs_[li * 8]);
    }
    __syncthreads();
    #pragma unroll
    for (int kk = 0; kk < 2; ++kk) {
      bf16v8 af[4], bfr[4];
      #pragma unroll
      for (int i = 0; i < 4; ++i) {
        af[i]  = *(const bf16v8*)&As_[(wm + i * 16 + l16) * 64 + kk * 32 + quad * 8];
        bfr[i] = *(const bf16v8*)&Bs_[(wn + i * 16 + l16) * 64 + kk * 32 + quad * 8];
      }
      #pragma unroll
      for (int i = 0; i < 4; ++i)
        #pragma unroll
        for (int j = 0; j < 4; ++j)
          acc[i][j] = MFMA16(af[i], bfr[j], acc[i][j]);
    }
  }
  #pragma unroll
  for (int i = 0; i < 4; ++i)
    #pragma unroll
    for (int j = 0; j < 4; ++j)
      #pragma unroll
      for (int r = 0; r < 4; ++r) {
        int m = m0 + wm + i * 16 + quad * 4 + r;
        int n = n0 + wn + j * 16 + l16;
        out[(size_t)m * EMB + n] = acc[i][j][r];
      }
}

// ---------------- launch ----------------

extern "C" void kernel_launch(void* const* d_in, const int* in_sizes, int n_in,
                              void* d_out, int out_size, void* d_ws, size_t ws_size,
                              hipStream_t stream) {
  const float* x     = (const float*)d_in[0];
  const float* w_qkv = (const float*)d_in[1];
  const float* w_out = (const float*)d_in[2];
  float* out = (float*)d_out;
  char* ws = (char*)d_ws;

  const size_t SZ  = (size_t)MROWS * EMB * sizeof(bf16);   // 16.78 MB
  const size_t SZ8 = (size_t)MROWS * EMB;                  // 8.39 MB (i8 plane)
  size_t off = 0;
  float* sums = (float*)ws;            off = 256;
  char*  wq8  = (char*)(ws + off);     off += (size_t)NQKV * EMB;               // 3.1 MB
  bf16*  wo_t = (bf16*)(ws + off);     off += (size_t)EMB * EMB * sizeof(bf16); // 2.1 MB
  char*  xq1  = (char*)(ws + off);     off += SZ8;
  char*  xq2  = (char*)(ws + off);     off += SZ8;
  bf16*  qh   = (bf16*)(ws + off);     off += SZ;
  bf16*  ql   = (bf16*)(ws + off);     off += SZ;
  bf16*  kh   = (bf16*)(ws + off);     off += SZ;
  bf16*  kl   = (bf16*)(ws + off);     off += SZ;
  bf16*  vt   = (bf16*)(ws + off);     off += SZ;  // written directly by gemm_qkv
  bf16*  ob   = (bf16*)xq1;   // x planes dead after gemm_qkv -> attn output spans xq1+xq2
  (void)in_sizes; (void)n_in; (void)out_size; (void)ws_size;

  zero2_kernel<<<1, 2, 0, stream>>>(sums);
  abs_sum_kernel<<<256, 256, 0, stream>>>(w_qkv, NQKV * EMB, &sums[0]);
  abs_sum_kernel<<<256, 256, 0, stream>>>(w_out, EMB * EMB, &sums[1]);
  ternarize_i8_kernel<<<(NQKV * EMB) / 256, 256, 0, stream>>>(w_qkv, NQKV * EMB, &sums[0], wq8);
  ternarize_bf16_kernel<<<(EMB * EMB) / 256, 256, 0, stream>>>(w_out, EMB * EMB, &sums[1], wo_t);
  quant_x_kernel<<<(MROWS * EMB) / 256, 256, 0, stream>>>(x, xq1, xq2, MROWS * EMB);
  gemm_qkv_kernel<<<dim3(MROWS / 128, NQKV / 128), 256, 0, stream>>>(xq1, xq2, wq8, qh, ql, kh, kl, vt);
  attn_kernel<<<dim3(8, BSZ * NHEAD), 256, 0, stream>>>(qh, ql, kh, kl, vt, ob);
  gemm_out_kernel<<<dim3(MROWS / 128, EMB / 128), 256, 0, stream>>>(ob, wo_t, out);
}